// Round 3
// baseline (357.175 us; speedup 1.0000x reference)
//
#include <hip/hip_runtime.h>
#include <hip/hip_cooperative_groups.h>

// Round 11: single cooperative mega-kernel (prep -> proj -> attn -> reduce)
// with grid.sync() between phases. Phase bodies identical to round 9
// (best measured): __syncthreads ping-pong proj, zero-barrier reg-direct attn.
// Falls back to the 4-kernel path if cooperative launch is rejected.

namespace cg = cooperative_groups;

typedef __bf16 bf16;
typedef __bf16 bf16x4 __attribute__((ext_vector_type(4)));
typedef __bf16 bf16x8 __attribute__((ext_vector_type(8)));
typedef float  f32x16 __attribute__((ext_vector_type(16)));

#define MFMA(a, b, c) __builtin_amdgcn_mfma_f32_32x32x16_bf16(a, b, c, 0, 0, 0)

constexpr int T = 4096, D = 1024, HS = 64;
constexpr int ROWS = 4 * T;                   // 16384
constexpr float QSCL = 0.045084220027797f;    // (1/32) * log2(e)

__device__ __forceinline__ void gld16(const void* g, void* l) {
    __builtin_amdgcn_global_load_lds(
        (const __attribute__((address_space(1))) unsigned int*)g,
        (__attribute__((address_space(3))) unsigned int*)l, 16, 0, 0);
}

__device__ inline f32x16 zero16() {
    f32x16 z;
#pragma unroll
    for (int i = 0; i < 16; ++i) z[i] = 0.f;
    return z;
}

// ---------------- phase bodies (shared by mega + fallback kernels) ----------------

// prep: Wt[192][1024] bf16 = concat(Wq^T*QSCL, Wk^T, Wv^T); one 64x64 tile/item
__device__ __forceinline__ void prep_body(int item, const float* Wq, const float* Wk,
        const float* Wv, bf16* Wt, float* Xf /* 64*68 floats */)
{
    const int tid = threadIdx.x;
    const int m = item >> 4, dt = item & 15;
    const float* W = (m == 0) ? Wq : ((m == 1) ? Wk : Wv);
    const int d0 = dt * 64;
#pragma unroll
    for (int j = 0; j < 4; ++j) {
        int i = tid + 256 * j;
        int dr = i >> 4, c4 = i & 15;
        float4 v = *(const float4*)(W + (size_t)(d0 + dr) * 64 + c4 * 4);
        *(float4*)&Xf[dr * 68 + c4 * 4] = v;
    }
    __syncthreads();
    const float scl = (m == 0) ? QSCL : 1.0f;
#pragma unroll
    for (int j = 0; j < 4; ++j) {
        int o = tid + 256 * j;
        int h = o >> 4, dc = o & 15;
        bf16x4 w;
#pragma unroll
        for (int k = 0; k < 4; ++k) w[k] = (bf16)(Xf[(dc * 4 + k) * 68 + h] * scl);
        *(bf16x4*)(Wt + (size_t)(m * 64 + h) * D + d0 + dc * 4) = w;
    }
}

// proj: one (64-row x-tile, which) item; ping-pong gld16 staging + __syncthreads
__device__ __forceinline__ void proj_body(int it, const float* x, const bf16* Wt,
        bf16* Qg, bf16* Kgt, bf16* Vgt,
        float* Xs /* 2*4096 floats */, short* Ws /* 2*4096 shorts */)
{
    const int tid = threadIdx.x;
    const int w = tid >> 6, lane = tid & 63, ln5 = lane & 31, hi = lane >> 5;
    const int tt = w & 1, hh = w >> 1;
    const int xcd = it & 7, t3 = it >> 3;
    const int which = t3 % 3, mlocal = t3 / 3;       // same x-tile -> same xcd
    const int r0 = (xcd * 32 + mlocal) * 64;
    const int wb = tid & 448;

    auto stage = [&](int kc, int buf) {
#pragma unroll
        for (int k2 = 0; k2 < 4; ++k2) {             // x tile 16 KB fp32
            int s = k2 * 256 + tid;
            int r = s >> 4, j = s & 15, u = j ^ (r & 15);
            gld16(x + (size_t)(r0 + r) * D + kc * 64 + u * 4,
                  &Xs[buf * 4096 + (k2 * 256 + wb) * 4]);
        }
#pragma unroll
        for (int k2 = 0; k2 < 2; ++k2) {             // W slice 8 KB bf16
            int s = k2 * 256 + tid;
            int h = s >> 3, j = s & 7, u = j ^ (h & 7);
            gld16(Wt + (size_t)(which * 64 + h) * D + kc * 64 + u * 8,
                  &Ws[buf * 4096 + (k2 * 256 + wb) * 8]);
        }
    };

    f32x16 acc = zero16();
    const int rx = tt * 32 + ln5;
    const int hq = hh * 32 + ln5;
    const int swz = ln5 & 7;

    stage(0, 0);
    __syncthreads();
    for (int kc = 0; kc < 16; ++kc) {
        const int cur = kc & 1;
        if (kc < 15) stage(kc + 1, cur ^ 1);
        const float* Xb = &Xs[cur * 4096];
        const short* Wb = &Ws[cur * 4096];
#pragma unroll
        for (int ks = 0; ks < 4; ++ks) {
            int u0 = ks * 4 + hi * 2;
            float4 a = *(const float4*)&Xb[rx * 64 + ((u0)     ^ (rx & 15)) * 4];
            float4 b = *(const float4*)&Xb[rx * 64 + ((u0 + 1) ^ (rx & 15)) * 4];
            bf16x8 fx;
            fx[0] = (bf16)a.x; fx[1] = (bf16)a.y; fx[2] = (bf16)a.z; fx[3] = (bf16)a.w;
            fx[4] = (bf16)b.x; fx[5] = (bf16)b.y; fx[6] = (bf16)b.z; fx[7] = (bf16)b.w;
            bf16x8 wf = *(const bf16x8*)&Wb[hq * 64 + (((ks * 2 + hi) ^ swz) * 8)];
            if (which < 2) acc = MFMA(wf, fx, acc);   // C^T (col = t)
            else           acc = MFMA(fx, wf, acc);   // C   (col = h)
        }
        __syncthreads();
    }

    if (which < 2) {
        int t = r0 + tt * 32 + ln5;
#pragma unroll
        for (int g = 0; g < 4; ++g) {
            int h0 = hh * 32 + 8 * g + 4 * hi;
            bf16x4 v;
#pragma unroll
            for (int k = 0; k < 4; ++k) v[k] = (bf16)acc[4 * g + k];
            if (which == 0) {
                *(bf16x4*)(Qg + (size_t)t * HS + h0) = v;
            } else {
                int j = (h0 >> 3) ^ (t & 7);
                *(bf16x4*)(Kgt + (size_t)t * HS + j * 8 + 4 * hi) = v;
            }
        }
    } else {
        int hr = hh * 32 + ln5;
#pragma unroll
        for (int g = 0; g < 4; ++g) {
            int t0 = tt * 32 + 8 * g + 4 * hi;
            bf16x4 v;
#pragma unroll
            for (int k = 0; k < 4; ++k) v[k] = (bf16)acc[4 * g + k];
            int j = (t0 >> 3) ^ (hr & 7);
            *(bf16x4*)(Vgt + (size_t)r0 * HS + hr * 64 + j * 8 + 4 * hi) = v;
        }
    }
}

// attn (round-9 zero-barrier reg-direct): block = 128 q-rows, wave = 64 q x 32 kr
__device__ __forceinline__ void attn_body(int bid, int split, const bf16* Qg,
        const bf16* Kgt, const bf16* Vgt, float* Op, float* Lp, float* out,
        short* PO /* 16384 shorts */, float* Lx /* 128 floats */)
{
    const int tid = threadIdx.x;
    const int w = tid >> 6, lane = tid & 63, ln5 = lane & 31, hi = lane >> 5;
    const int wq = w & 1, wk = w >> 1;

    int b, qt, half;
    if (split == 4) {
        int rest = bid >> 3; qt = rest & 31;
        int combo = (bid & 7) + 8 * (rest >> 5);     // (b,half) pinned per XCD
        b = combo >> 2; half = combo & 3;
    } else if (split == 2) {
        int c2 = bid & 7; b = c2 >> 1; half = c2 & 1; qt = bid >> 3;
    } else { b = bid & 3; half = 0; qt = bid >> 2; }

    const int rbase = b * T;
    const int seg = T / split;
    const int kb0 = rbase + half * seg;
    const int nc = seg / 64;
    const int qrow0 = rbase + qt * 128 + wq * 64;

    bf16x8 bq[2][4];
    {
        const bf16* qp = Qg + (size_t)(qrow0 + ln5) * HS + hi * 8;
#pragma unroll
        for (int qs = 0; qs < 2; ++qs)
#pragma unroll
            for (int ks = 0; ks < 4; ++ks)
                bq[qs][ks] = *(const bf16x8*)(qp + (size_t)qs * 32 * HS + ks * 16);
    }

    const bf16* Kc = Kgt + (size_t)kb0 * HS;
    const bf16* Vc = Vgt + (size_t)kb0 * HS;

    f32x16 O00 = zero16(), O01 = zero16(), O10 = zero16(), O11 = zero16();
    float l0 = 0.f, l1 = 0.f;
    short* Pw = &PO[w * 2560];
    const int swz = ln5 & 7;
    const int krow = (wk * 32 + ln5) * 64;           // K frag row (shorts)
    const int ko0 = krow + ((0 + hi) ^ swz) * 8;
    const int ko1 = krow + ((2 + hi) ^ swz) * 8;
    const int ko2 = krow + ((4 + hi) ^ swz) * 8;
    const int ko3 = krow + ((6 + hi) ^ swz) * 8;
    const int ku0 = ((wk * 4 + 0 + hi) ^ swz) * 8;   // PV ks=0
    const int ku1 = ((wk * 4 + 2 + hi) ^ swz) * 8;   // PV ks=1
    const int vr0 = ln5 * 64, vr1 = (32 + ln5) * 64;

    bf16x8 kf0 = *(const bf16x8*)(Kc + ko0);
    bf16x8 kf1 = *(const bf16x8*)(Kc + ko1);
    bf16x8 kf2 = *(const bf16x8*)(Kc + ko2);
    bf16x8 kf3 = *(const bf16x8*)(Kc + ko3);

    for (int c = 0; c < nc; ++c) {
        const bf16* Vb = Vc + (size_t)c * 4096;
        bf16x8 v00 = *(const bf16x8*)(Vb + vr0 + ku0);
        bf16x8 v01 = *(const bf16x8*)(Vb + vr0 + ku1);
        bf16x8 v10 = *(const bf16x8*)(Vb + vr1 + ku0);
        bf16x8 v11 = *(const bf16x8*)(Vb + vr1 + ku1);
        const bool pf = (c + 1 < nc);
        bf16x8 kn0, kn1, kn2, kn3;
        if (pf) {
            const bf16* Kn = Kc + (size_t)(c + 1) * 4096;
            kn0 = *(const bf16x8*)(Kn + ko0);
            kn1 = *(const bf16x8*)(Kn + ko1);
            kn2 = *(const bf16x8*)(Kn + ko2);
            kn3 = *(const bf16x8*)(Kn + ko3);
        }

        f32x16 S0 = zero16(), S1 = zero16();
        S0 = MFMA(kf0, bq[0][0], S0); S1 = MFMA(kf0, bq[1][0], S1);
        S0 = MFMA(kf1, bq[0][1], S0); S1 = MFMA(kf1, bq[1][1], S1);
        S0 = MFMA(kf2, bq[0][2], S0); S1 = MFMA(kf2, bq[1][2], S1);
        S0 = MFMA(kf3, bq[0][3], S0); S1 = MFMA(kf3, bq[1][3], S1);

#pragma unroll
        for (int g = 0; g < 4; ++g) {
            float p0 = __builtin_amdgcn_exp2f(S0[4 * g + 0]);
            float p1 = __builtin_amdgcn_exp2f(S0[4 * g + 1]);
            float p2 = __builtin_amdgcn_exp2f(S0[4 * g + 2]);
            float p3 = __builtin_amdgcn_exp2f(S0[4 * g + 3]);
            l0 += (p0 + p1) + (p2 + p3);
            bf16x4 pv; pv[0] = (bf16)p0; pv[1] = (bf16)p1; pv[2] = (bf16)p2; pv[3] = (bf16)p3;
            *(bf16x4*)&Pw[ln5 * 40 + 8 * g + 4 * hi] = pv;
        }
#pragma unroll
        for (int g = 0; g < 4; ++g) {
            float p0 = __builtin_amdgcn_exp2f(S1[4 * g + 0]);
            float p1 = __builtin_amdgcn_exp2f(S1[4 * g + 1]);
            float p2 = __builtin_amdgcn_exp2f(S1[4 * g + 2]);
            float p3 = __builtin_amdgcn_exp2f(S1[4 * g + 3]);
            l1 += (p0 + p1) + (p2 + p3);
            bf16x4 pv; pv[0] = (bf16)p0; pv[1] = (bf16)p1; pv[2] = (bf16)p2; pv[3] = (bf16)p3;
            *(bf16x4*)&Pw[(32 + ln5) * 40 + 8 * g + 4 * hi] = pv;
        }

        {
            bf16x8 pf0 = *(const bf16x8*)&Pw[ln5 * 40 + hi * 8];
            bf16x8 pf1 = *(const bf16x8*)&Pw[(32 + ln5) * 40 + hi * 8];
            O00 = MFMA(v00, pf0, O00);
            O01 = MFMA(v00, pf1, O01);
            O10 = MFMA(v10, pf0, O10);
            O11 = MFMA(v10, pf1, O11);
            pf0 = *(const bf16x8*)&Pw[ln5 * 40 + 16 + hi * 8];
            pf1 = *(const bf16x8*)&Pw[(32 + ln5) * 40 + 16 + hi * 8];
            O00 = MFMA(v01, pf0, O00);
            O01 = MFMA(v01, pf1, O01);
            O10 = MFMA(v11, pf0, O10);
            O11 = MFMA(v11, pf1, O11);
        }

        if (pf) { kf0 = kn0; kf1 = kn1; kf2 = kn2; kf3 = kn3; }
    }

    l0 += __shfl_xor(l0, 32, 64);
    l1 += __shfl_xor(l1, 32, 64);

    __syncthreads();                                 // all waves done reading Pw
    float* Ox = (float*)&PO[0];                      // [wq][h 64][q 64]
    if (wk == 1) {
#pragma unroll
        for (int g = 0; g < 4; ++g)
#pragma unroll
            for (int k = 0; k < 4; ++k) {
                int h0 = 8 * g + 4 * hi + k;
                Ox[wq * 4096 + h0 * 64 + ln5]             = O00[4 * g + k];
                Ox[wq * 4096 + h0 * 64 + 32 + ln5]        = O01[4 * g + k];
                Ox[wq * 4096 + (32 + h0) * 64 + ln5]      = O10[4 * g + k];
                Ox[wq * 4096 + (32 + h0) * 64 + 32 + ln5] = O11[4 * g + k];
            }
        if (hi == 0) { Lx[wq * 64 + ln5] = l0; Lx[wq * 64 + 32 + ln5] = l1; }
    }
    __syncthreads();
    if (wk == 0) {
#pragma unroll
        for (int g = 0; g < 4; ++g)
#pragma unroll
            for (int k = 0; k < 4; ++k) {
                int h0 = 8 * g + 4 * hi + k;
                O00[4 * g + k] += Ox[wq * 4096 + h0 * 64 + ln5];
                O01[4 * g + k] += Ox[wq * 4096 + h0 * 64 + 32 + ln5];
                O10[4 * g + k] += Ox[wq * 4096 + (32 + h0) * 64 + ln5];
                O11[4 * g + k] += Ox[wq * 4096 + (32 + h0) * 64 + 32 + ln5];
            }
        l0 += Lx[wq * 64 + ln5];
        l1 += Lx[wq * 64 + 32 + ln5];

        int q0 = qrow0 + ln5, q1 = qrow0 + 32 + ln5;
        if (split == 1) {
            float i0 = 1.0f / l0, i1 = 1.0f / l1;
#pragma unroll
            for (int g = 0; g < 4; ++g) {
                int h0 = 8 * g + 4 * hi;
                float4 o;
                o.x = O00[4*g+0]*i0; o.y = O00[4*g+1]*i0; o.z = O00[4*g+2]*i0; o.w = O00[4*g+3]*i0;
                *(float4*)(out + (size_t)q0 * HS + h0) = o;
                o.x = O01[4*g+0]*i1; o.y = O01[4*g+1]*i1; o.z = O01[4*g+2]*i1; o.w = O01[4*g+3]*i1;
                *(float4*)(out + (size_t)q1 * HS + h0) = o;
                o.x = O10[4*g+0]*i0; o.y = O10[4*g+1]*i0; o.z = O10[4*g+2]*i0; o.w = O10[4*g+3]*i0;
                *(float4*)(out + (size_t)q0 * HS + 32 + h0) = o;
                o.x = O11[4*g+0]*i1; o.y = O11[4*g+1]*i1; o.z = O11[4*g+2]*i1; o.w = O11[4*g+3]*i1;
                *(float4*)(out + (size_t)q1 * HS + 32 + h0) = o;
            }
        } else {
            float* Od = Op + (size_t)half * ROWS * HS;
#pragma unroll
            for (int g = 0; g < 4; ++g) {
                int h0 = 8 * g + 4 * hi;
                float4 o;
                o.x = O00[4*g+0]; o.y = O00[4*g+1]; o.z = O00[4*g+2]; o.w = O00[4*g+3];
                *(float4*)(Od + (size_t)q0 * HS + h0) = o;
                o.x = O01[4*g+0]; o.y = O01[4*g+1]; o.z = O01[4*g+2]; o.w = O01[4*g+3];
                *(float4*)(Od + (size_t)q1 * HS + h0) = o;
                o.x = O10[4*g+0]; o.y = O10[4*g+1]; o.z = O10[4*g+2]; o.w = O10[4*g+3];
                *(float4*)(Od + (size_t)q0 * HS + 32 + h0) = o;
                o.x = O11[4*g+0]; o.y = O11[4*g+1]; o.z = O11[4*g+2]; o.w = O11[4*g+3];
                *(float4*)(Od + (size_t)q1 * HS + 32 + h0) = o;
            }
            if (hi == 0) {
                Lp[half * ROWS + q0] = l0;
                Lp[half * ROWS + q1] = l1;
            }
        }
    }
}

__device__ __forceinline__ void reduce_body(int it, int split,
        const float* Op, const float* Lp, float* out)
{
    int idx = it * 256 + threadIdx.x;                // float4 index
    int row = idx >> 4;
    float4 s; s.x = s.y = s.z = s.w = 0.f;
    float lsum = 0.f;
    for (int h = 0; h < split; ++h) {
        float4 a = *(const float4*)(Op + (size_t)h * ROWS * HS + (size_t)idx * 4);
        s.x += a.x; s.y += a.y; s.z += a.z; s.w += a.w;
        lsum += Lp[h * ROWS + row];
    }
    float inv = 1.0f / lsum;
    s.x *= inv; s.y *= inv; s.z *= inv; s.w *= inv;
    *(float4*)(out + (size_t)idx * 4) = s;
}

// ---------------- mega kernel (cooperative) ----------------

__global__ __launch_bounds__(256, 2) void mega(
    const float* __restrict__ x, const float* __restrict__ Wq,
    const float* __restrict__ Wk, const float* __restrict__ Wv,
    bf16* __restrict__ Wt, bf16* __restrict__ Qg, bf16* __restrict__ Kgt,
    bf16* __restrict__ Vgt, float* __restrict__ Op, float* __restrict__ Lp,
    float* __restrict__ out)
{
    // union: prep 17408 B | proj 49152 B | attn 33280 B
    __shared__ __align__(16) char smem[49664];
    const int bid = blockIdx.x;
    cg::grid_group grid = cg::this_grid();

    // phase 0: Wt prep (48 items)
    if (bid < 48) prep_body(bid, Wq, Wk, Wv, Wt, (float*)smem);
    grid.sync();

    // phase 1: qkv projection (768 items over 512 blocks; b and b+256 share a
    // CU under XCD round-robin dispatch -> 3 items/CU, pinning preserved)
    for (int it = bid; it < 768; it += 512)
        proj_body(it, x, Wt, Qg, Kgt, Vgt, (float*)smem, (short*)(smem + 32768));
    grid.sync();

    // phase 2: attention, split=4 (512 items, 1:1)
    attn_body(bid, 4, Qg, Kgt, Vgt, Op, Lp, out,
              (short*)smem, (float*)(smem + 32768));
    grid.sync();

    // phase 3: reduce (1024 items over 512 blocks)
    for (int it = bid; it < 1024; it += 512)
        reduce_body(it, 4, Op, Lp, out);
}

// ---------------- fallback standalone kernels (round-9 path) ----------------

__global__ __launch_bounds__(256) void prep_wt(
    const float* __restrict__ Wq, const float* __restrict__ Wk,
    const float* __restrict__ Wv, bf16* __restrict__ Wt)
{
    __shared__ float Xf[64 * 68];
    prep_body(blockIdx.x, Wq, Wk, Wv, Wt, Xf);
}

__global__ __launch_bounds__(256, 3) void qkv_proj(
    const float* __restrict__ x, const bf16* __restrict__ Wt,
    bf16* __restrict__ Qg, bf16* __restrict__ Kgt, bf16* __restrict__ Vgt)
{
    __shared__ __align__(16) float Xs[2 * 4096];
    __shared__ __align__(16) short Ws[2 * 4096];
    proj_body(blockIdx.x, x, Wt, Qg, Kgt, Vgt, Xs, Ws);
}

__global__ __launch_bounds__(256, 2) void attn(
    const bf16* __restrict__ Qg, const bf16* __restrict__ Kgt,
    const bf16* __restrict__ Vgt, float* __restrict__ Op,
    float* __restrict__ Lp, float* __restrict__ out, int split)
{
    __shared__ __align__(16) short PO[16384];
    __shared__ float Lx[128];
    attn_body(blockIdx.x, split, Qg, Kgt, Vgt, Op, Lp, out, PO, Lx);
}

__global__ __launch_bounds__(256) void attn_reduce(
    const float* __restrict__ Op, const float* __restrict__ Lp,
    float* __restrict__ out, int split)
{
    reduce_body(blockIdx.x, split, Op, Lp, out);
}

// ---------------- launch ----------------

extern "C" void kernel_launch(void* const* d_in, const int* in_sizes, int n_in,
                              void* d_out, int out_size, void* d_ws, size_t ws_size,
                              hipStream_t stream)
{
    const float* x  = (const float*)d_in[0];
    const float* Wq = (const float*)d_in[1];
    const float* Wk = (const float*)d_in[2];
    const float* Wv = (const float*)d_in[3];
    float* out = (float*)d_out;

    char* ws = (char*)d_ws;
    bf16* Qg  = (bf16*)(ws);                          // 2 MB  [16384][64]
    bf16* Kgt = (bf16*)(ws + ((size_t)2 << 20));      // 2 MB  tiled+swizzled
    bf16* Vgt = (bf16*)(ws + ((size_t)4 << 20));      // 2 MB  tiled+swizzled
    bf16* Wt  = (bf16*)(ws + ((size_t)6 << 20));      // 384 KB [192][1024]
    float* Lp = (float*)(ws + ((size_t)6 << 20));     // overlays Wt (dead after proj)
    float* Op = (float*)(ws + ((size_t)6 << 20) + ((size_t)1 << 19));

    const size_t base = ((size_t)6 << 20) + ((size_t)1 << 19);
    const bool can4 = ws_size >= base + (size_t)4 * ROWS * HS * sizeof(float);

    if (can4) {
        void* kargs[] = {(void*)&x, (void*)&Wq, (void*)&Wk, (void*)&Wv,
                         (void*)&Wt, (void*)&Qg, (void*)&Kgt, (void*)&Vgt,
                         (void*)&Op, (void*)&Lp, (void*)&out};
        hipError_t e = hipLaunchCooperativeKernel((const void*)mega, dim3(512),
                                                  dim3(256), kargs, 0, stream);
        if (e == hipSuccess) return;
        (void)hipGetLastError();                      // clear sticky error, fall back
    }

    int split = 1;
    if (can4) split = 4;
    else if (ws_size >= base + (size_t)2 * ROWS * HS * sizeof(float)) split = 2;

    prep_wt<<<48, 256, 0, stream>>>(Wq, Wk, Wv, Wt);
    qkv_proj<<<768, 256, 0, stream>>>(x, Wt, Qg, Kgt, Vgt);
    attn<<<128 * split, 256, 0, stream>>>(Qg, Kgt, Vgt, Op, Lp, out, split);
    if (split > 1)
        attn_reduce<<<(ROWS * HS / 4) / 256, 256, 0, stream>>>(Op, Lp, out, split);
}

// Round 5
// 142.943 us; speedup vs baseline: 2.4987x; 2.4987x over previous
//
#include <hip/hip_runtime.h>

// Round 13 (= round 12 resubmit; container infra failure last round).
// Fused QKV projection (x staged ONCE per tile, 3 outputs/block).
//  - proj: grid 256 (one 64-row x-tile per block, XCD-pinned). X staged
//    fp32->reg->cvt->bf16 LDS (issue-early/write-late); W (all 192 rows)
//    staged via gld16. Each wave: 3 accumulators (Q,K,V), 12 MFMA/chunk.
//    Replaces 3x re-read of x (3 which-blocks) with a single read.
//  - attn: round-9 zero-barrier reg-direct (best measured). prep/reduce same.

typedef __bf16 bf16;
typedef __bf16 bf16x4 __attribute__((ext_vector_type(4)));
typedef __bf16 bf16x8 __attribute__((ext_vector_type(8)));
typedef float  f32x16 __attribute__((ext_vector_type(16)));

#define MFMA(a, b, c) __builtin_amdgcn_mfma_f32_32x32x16_bf16(a, b, c, 0, 0, 0)

constexpr int T = 4096, D = 1024, HS = 64;
constexpr int ROWS = 4 * T;                   // 16384
constexpr float QSCL = 0.045084220027797f;    // (1/32) * log2(e)

__device__ __forceinline__ void gld16(const void* g, void* l) {
    __builtin_amdgcn_global_load_lds(
        (const __attribute__((address_space(1))) unsigned int*)g,
        (__attribute__((address_space(3))) unsigned int*)l, 16, 0, 0);
}

__device__ inline f32x16 zero16() {
    f32x16 z;
#pragma unroll
    for (int i = 0; i < 16; ++i) z[i] = 0.f;
    return z;
}

// ---- prep: Wt[192][1024] bf16 = concat(Wq^T*QSCL, Wk^T, Wv^T) ----
__global__ __launch_bounds__(256) void prep_wt(
    const float* __restrict__ Wq, const float* __restrict__ Wk,
    const float* __restrict__ Wv, bf16* __restrict__ Wt)
{
    __shared__ float Xf[64 * 68];
    const int m = blockIdx.x >> 4, dt = blockIdx.x & 15;
    const float* W = (m == 0) ? Wq : ((m == 1) ? Wk : Wv);
    const int d0 = dt * 64;
#pragma unroll
    for (int j = 0; j < 4; ++j) {
        int i = threadIdx.x + 256 * j;
        int dr = i >> 4, c4 = i & 15;
        float4 v = *(const float4*)(W + (size_t)(d0 + dr) * 64 + c4 * 4);
        *(float4*)&Xf[dr * 68 + c4 * 4] = v;
    }
    __syncthreads();
    const float scl = (m == 0) ? QSCL : 1.0f;
#pragma unroll
    for (int j = 0; j < 4; ++j) {
        int o = threadIdx.x + 256 * j;
        int h = o >> 4, dc = o & 15;
        bf16x4 w;
#pragma unroll
        for (int k = 0; k < 4; ++k) w[k] = (bf16)(Xf[(dc * 4 + k) * 68 + h] * scl);
        *(bf16x4*)(Wt + (size_t)(m * 64 + h) * D + d0 + dc * 4) = w;
    }
}

// ---- fused projection: grid 256 = 8 xcd x 32 mtile; Q+K+V per block ----
__global__ __launch_bounds__(256) void qkv_proj(
    const float* __restrict__ x, const bf16* __restrict__ Wt,
    bf16* __restrict__ Qg, bf16* __restrict__ Kgt, bf16* __restrict__ Vgt)
{
    __shared__ __align__(16) bf16  Xb[2][64 * 64];   // swizzled granule: [r][u^(r&7)]
    __shared__ __align__(16) short Ws[2][192 * 64];  // swizzled: [h][u^(h&7)]
    const int tid = threadIdx.x;
    const int w = tid >> 6, lane = tid & 63, ln5 = lane & 31, hi = lane >> 5;
    const int tt = w & 1, hh = w >> 1;
    const int xcd = blockIdx.x & 7, mlocal = blockIdx.x >> 3;
    const int r0 = (xcd * 32 + mlocal) * 64;
    const int wb = tid & 448;

    // W: 24 KB (192 h x 64 d) bf16 via gld16, pre-swizzled global source
    auto stageW = [&](int kc, int buf) {
#pragma unroll
        for (int k2 = 0; k2 < 6; ++k2) {
            int s = k2 * 256 + tid;
            int h = s >> 3, j = s & 7, u = j ^ (h & 7);
            gld16(Wt + (size_t)h * D + kc * 64 + u * 8,
                  &Ws[buf][(k2 * 256 + wb) * 8]);
        }
    };
    // X: fp32 global -> regs (issue early) -> cvt bf16 -> LDS (write late)
    float4 xra[2], xrb[2];
    auto stageX_load = [&](int kc) {
#pragma unroll
        for (int k = 0; k < 2; ++k) {
            int e = k * 256 + tid;
            int r = e >> 3, d0 = (e & 7) * 8;
            const float* src = x + (size_t)(r0 + r) * D + kc * 64 + d0;
            xra[k] = *(const float4*)src;
            xrb[k] = *(const float4*)(src + 4);
        }
    };
    auto stageX_write = [&](int buf) {
#pragma unroll
        for (int k = 0; k < 2; ++k) {
            int e = k * 256 + tid;
            int r = e >> 3, d0 = (e & 7) * 8;
            bf16x8 v;
            v[0] = (bf16)xra[k].x; v[1] = (bf16)xra[k].y;
            v[2] = (bf16)xra[k].z; v[3] = (bf16)xra[k].w;
            v[4] = (bf16)xrb[k].x; v[5] = (bf16)xrb[k].y;
            v[6] = (bf16)xrb[k].z; v[7] = (bf16)xrb[k].w;
            *(bf16x8*)&Xb[buf][r * 64 + (((d0 >> 3) ^ (r & 7)) * 8)] = v;
        }
    };

    f32x16 acc0 = zero16(), acc1 = zero16(), acc2 = zero16();
    const int rx = tt * 32 + ln5;
    const int hq = hh * 32 + ln5;
    const int swz = ln5 & 7;

    stageX_load(0); stageW(0, 0); stageX_write(0);
    __syncthreads();
    for (int kc = 0; kc < 16; ++kc) {
        const int cur = kc & 1;
        if (kc < 15) { stageW(kc + 1, cur ^ 1); stageX_load(kc + 1); }
        const bf16*  Xc = &Xb[cur][0];
        const short* Wb = &Ws[cur][0];
#pragma unroll
        for (int ks = 0; ks < 4; ++ks) {
            int g = (ks * 2 + hi) ^ swz;
            bf16x8 fx = *(const bf16x8*)&Xc[rx * 64 + g * 8];
            bf16x8 w0 = *(const bf16x8*)&Wb[(hq)       * 64 + g * 8];
            bf16x8 w1 = *(const bf16x8*)&Wb[(64 + hq)  * 64 + g * 8];
            bf16x8 w2 = *(const bf16x8*)&Wb[(128 + hq) * 64 + g * 8];
            acc0 = MFMA(w0, fx, acc0);   // Q: C^T (col = t)
            acc1 = MFMA(w1, fx, acc1);   // K: C^T (col = t)
            acc2 = MFMA(fx, w2, acc2);   // V: C   (col = h)
        }
        if (kc < 15) stageX_write(cur ^ 1);
        __syncthreads();
    }

    // Q store (linear [t][h])
    {
        int t = r0 + tt * 32 + ln5;
#pragma unroll
        for (int g = 0; g < 4; ++g) {
            int h0 = hh * 32 + 8 * g + 4 * hi;
            bf16x4 v;
#pragma unroll
            for (int k = 0; k < 4; ++k) v[k] = (bf16)acc0[4 * g + k];
            *(bf16x4*)(Qg + (size_t)t * HS + h0) = v;
        }
    }
    // K store (tiled+swizzled [t][j^..])
    {
        int t = r0 + tt * 32 + ln5;
#pragma unroll
        for (int g = 0; g < 4; ++g) {
            int h0 = hh * 32 + 8 * g + 4 * hi;
            bf16x4 v;
#pragma unroll
            for (int k = 0; k < 4; ++k) v[k] = (bf16)acc1[4 * g + k];
            int j = (h0 >> 3) ^ (t & 7);
            *(bf16x4*)(Kgt + (size_t)t * HS + j * 8 + 4 * hi) = v;
        }
    }
    // V store (tiled V^T [tile][h][t-swizzled])
    {
        int hr = hh * 32 + ln5;
#pragma unroll
        for (int g = 0; g < 4; ++g) {
            int t0 = tt * 32 + 8 * g + 4 * hi;
            bf16x4 v;
#pragma unroll
            for (int k = 0; k < 4; ++k) v[k] = (bf16)acc2[4 * g + k];
            int j = (t0 >> 3) ^ (hr & 7);
            *(bf16x4*)(Vgt + (size_t)r0 * HS + hr * 64 + j * 8 + 4 * hi) = v;
        }
    }
}

// ---- attention: block = 128 q-rows; wave = 64 q-cols x 32-kr half-chunk ----
// Zero-barrier k-loop; K/V fragments loaded global->register (round 9).
__global__ __launch_bounds__(256, 2) void attn(
    const bf16* __restrict__ Qg, const bf16* __restrict__ Kgt,
    const bf16* __restrict__ Vgt, float* __restrict__ Op,
    float* __restrict__ Lp, float* __restrict__ out, int split)
{
    __shared__ __align__(16) short PO[16384];        // 32 KB: P scratch / Ox overlay
    __shared__ float Lx[128];

    const int tid = threadIdx.x;
    const int w = tid >> 6, lane = tid & 63, ln5 = lane & 31, hi = lane >> 5;
    const int wq = w & 1, wk = w >> 1;

    int b, qt, half;
    if (split == 4) {
        int rest = blockIdx.x >> 3; qt = rest & 31;
        int combo = (blockIdx.x & 7) + 8 * (rest >> 5);   // (b,half) pinned per XCD
        b = combo >> 2; half = combo & 3;
    } else if (split == 2) {
        int c2 = blockIdx.x & 7; b = c2 >> 1; half = c2 & 1; qt = blockIdx.x >> 3;
    } else { b = blockIdx.x & 3; half = 0; qt = blockIdx.x >> 2; }

    const int rbase = b * T;
    const int seg = T / split;
    const int kb0 = rbase + half * seg;
    const int nc = seg / 64;
    const int qrow0 = rbase + qt * 128 + wq * 64;

    bf16x8 bq[2][4];
    {
        const bf16* qp = Qg + (size_t)(qrow0 + ln5) * HS + hi * 8;
#pragma unroll
        for (int qs = 0; qs < 2; ++qs)
#pragma unroll
            for (int ks = 0; ks < 4; ++ks)
                bq[qs][ks] = *(const bf16x8*)(qp + (size_t)qs * 32 * HS + ks * 16);
    }

    const bf16* Kc = Kgt + (size_t)kb0 * HS;
    const bf16* Vc = Vgt + (size_t)kb0 * HS;

    f32x16 O00 = zero16(), O01 = zero16(), O10 = zero16(), O11 = zero16();
    float l0 = 0.f, l1 = 0.f;
    short* Pw = &PO[w * 2560];
    const int swz = ln5 & 7;
    const int krow = (wk * 32 + ln5) * 64;           // K frag row (shorts)
    const int ko0 = krow + ((0 + hi) ^ swz) * 8;
    const int ko1 = krow + ((2 + hi) ^ swz) * 8;
    const int ko2 = krow + ((4 + hi) ^ swz) * 8;
    const int ko3 = krow + ((6 + hi) ^ swz) * 8;
    const int ku0 = ((wk * 4 + 0 + hi) ^ swz) * 8;   // PV ks=0
    const int ku1 = ((wk * 4 + 2 + hi) ^ swz) * 8;   // PV ks=1
    const int vr0 = ln5 * 64, vr1 = (32 + ln5) * 64;

    bf16x8 kf0 = *(const bf16x8*)(Kc + ko0);
    bf16x8 kf1 = *(const bf16x8*)(Kc + ko1);
    bf16x8 kf2 = *(const bf16x8*)(Kc + ko2);
    bf16x8 kf3 = *(const bf16x8*)(Kc + ko3);

    for (int c = 0; c < nc; ++c) {
        const bf16* Vb = Vc + (size_t)c * 4096;
        bf16x8 v00 = *(const bf16x8*)(Vb + vr0 + ku0);
        bf16x8 v01 = *(const bf16x8*)(Vb + vr0 + ku1);
        bf16x8 v10 = *(const bf16x8*)(Vb + vr1 + ku0);
        bf16x8 v11 = *(const bf16x8*)(Vb + vr1 + ku1);
        const bool pf = (c + 1 < nc);
        bf16x8 kn0, kn1, kn2, kn3;
        if (pf) {
            const bf16* Kn = Kc + (size_t)(c + 1) * 4096;
            kn0 = *(const bf16x8*)(Kn + ko0);
            kn1 = *(const bf16x8*)(Kn + ko1);
            kn2 = *(const bf16x8*)(Kn + ko2);
            kn3 = *(const bf16x8*)(Kn + ko3);
        }

        f32x16 S0 = zero16(), S1 = zero16();
        S0 = MFMA(kf0, bq[0][0], S0); S1 = MFMA(kf0, bq[1][0], S1);
        S0 = MFMA(kf1, bq[0][1], S0); S1 = MFMA(kf1, bq[1][1], S1);
        S0 = MFMA(kf2, bq[0][2], S0); S1 = MFMA(kf2, bq[1][2], S1);
        S0 = MFMA(kf3, bq[0][3], S0); S1 = MFMA(kf3, bq[1][3], S1);

#pragma unroll
        for (int g = 0; g < 4; ++g) {
            float p0 = __builtin_amdgcn_exp2f(S0[4 * g + 0]);
            float p1 = __builtin_amdgcn_exp2f(S0[4 * g + 1]);
            float p2 = __builtin_amdgcn_exp2f(S0[4 * g + 2]);
            float p3 = __builtin_amdgcn_exp2f(S0[4 * g + 3]);
            l0 += (p0 + p1) + (p2 + p3);
            bf16x4 pv; pv[0] = (bf16)p0; pv[1] = (bf16)p1; pv[2] = (bf16)p2; pv[3] = (bf16)p3;
            *(bf16x4*)&Pw[ln5 * 40 + 8 * g + 4 * hi] = pv;
        }
#pragma unroll
        for (int g = 0; g < 4; ++g) {
            float p0 = __builtin_amdgcn_exp2f(S1[4 * g + 0]);
            float p1 = __builtin_amdgcn_exp2f(S1[4 * g + 1]);
            float p2 = __builtin_amdgcn_exp2f(S1[4 * g + 2]);
            float p3 = __builtin_amdgcn_exp2f(S1[4 * g + 3]);
            l1 += (p0 + p1) + (p2 + p3);
            bf16x4 pv; pv[0] = (bf16)p0; pv[1] = (bf16)p1; pv[2] = (bf16)p2; pv[3] = (bf16)p3;
            *(bf16x4*)&Pw[(32 + ln5) * 40 + 8 * g + 4 * hi] = pv;
        }

        {
            bf16x8 pf0 = *(const bf16x8*)&Pw[ln5 * 40 + hi * 8];
            bf16x8 pf1 = *(const bf16x8*)&Pw[(32 + ln5) * 40 + hi * 8];
            O00 = MFMA(v00, pf0, O00);
            O01 = MFMA(v00, pf1, O01);
            O10 = MFMA(v10, pf0, O10);
            O11 = MFMA(v10, pf1, O11);
            pf0 = *(const bf16x8*)&Pw[ln5 * 40 + 16 + hi * 8];
            pf1 = *(const bf16x8*)&Pw[(32 + ln5) * 40 + 16 + hi * 8];
            O00 = MFMA(v01, pf0, O00);
            O01 = MFMA(v01, pf1, O01);
            O10 = MFMA(v11, pf0, O10);
            O11 = MFMA(v11, pf1, O11);
        }

        if (pf) { kf0 = kn0; kf1 = kn1; kf2 = kn2; kf3 = kn3; }
    }

    l0 += __shfl_xor(l0, 32, 64);
    l1 += __shfl_xor(l1, 32, 64);

    __syncthreads();                                 // all waves done reading Pw
    float* Ox = (float*)&PO[0];                      // [wq][h 64][q 64]
    if (wk == 1) {
#pragma unroll
        for (int g = 0; g < 4; ++g)
#pragma unroll
            for (int k = 0; k < 4; ++k) {
                int h0 = 8 * g + 4 * hi + k;
                Ox[wq * 4096 + h0 * 64 + ln5]             = O00[4 * g + k];
                Ox[wq * 4096 + h0 * 64 + 32 + ln5]        = O01[4 * g + k];
                Ox[wq * 4096 + (32 + h0) * 64 + ln5]      = O10[4 * g + k];
                Ox[wq * 4096 + (32 + h0) * 64 + 32 + ln5] = O11[4 * g + k];
            }
        if (hi == 0) { Lx[wq * 64 + ln5] = l0; Lx[wq * 64 + 32 + ln5] = l1; }
    }
    __syncthreads();
    if (wk == 0) {
#pragma unroll
        for (int g = 0; g < 4; ++g)
#pragma unroll
            for (int k = 0; k < 4; ++k) {
                int h0 = 8 * g + 4 * hi + k;
                O00[4 * g + k] += Ox[wq * 4096 + h0 * 64 + ln5];
                O01[4 * g + k] += Ox[wq * 4096 + h0 * 64 + 32 + ln5];
                O10[4 * g + k] += Ox[wq * 4096 + (32 + h0) * 64 + ln5];
                O11[4 * g + k] += Ox[wq * 4096 + (32 + h0) * 64 + 32 + ln5];
            }
        l0 += Lx[wq * 64 + ln5];
        l1 += Lx[wq * 64 + 32 + ln5];

        int q0 = qrow0 + ln5, q1 = qrow0 + 32 + ln5;
        if (split == 1) {
            float i0 = 1.0f / l0, i1 = 1.0f / l1;
#pragma unroll
            for (int g = 0; g < 4; ++g) {
                int h0 = 8 * g + 4 * hi;
                float4 o;
                o.x = O00[4*g+0]*i0; o.y = O00[4*g+1]*i0; o.z = O00[4*g+2]*i0; o.w = O00[4*g+3]*i0;
                *(float4*)(out + (size_t)q0 * HS + h0) = o;
                o.x = O01[4*g+0]*i1; o.y = O01[4*g+1]*i1; o.z = O01[4*g+2]*i1; o.w = O01[4*g+3]*i1;
                *(float4*)(out + (size_t)q1 * HS + h0) = o;
                o.x = O10[4*g+0]*i0; o.y = O10[4*g+1]*i0; o.z = O10[4*g+2]*i0; o.w = O10[4*g+3]*i0;
                *(float4*)(out + (size_t)q0 * HS + 32 + h0) = o;
                o.x = O11[4*g+0]*i1; o.y = O11[4*g+1]*i1; o.z = O11[4*g+2]*i1; o.w = O11[4*g+3]*i1;
                *(float4*)(out + (size_t)q1 * HS + 32 + h0) = o;
            }
        } else {
            float* Od = Op + (size_t)half * ROWS * HS;
#pragma unroll
            for (int g = 0; g < 4; ++g) {
                int h0 = 8 * g + 4 * hi;
                float4 o;
                o.x = O00[4*g+0]; o.y = O00[4*g+1]; o.z = O00[4*g+2]; o.w = O00[4*g+3];
                *(float4*)(Od + (size_t)q0 * HS + h0) = o;
                o.x = O01[4*g+0]; o.y = O01[4*g+1]; o.z = O01[4*g+2]; o.w = O01[4*g+3];
                *(float4*)(Od + (size_t)q1 * HS + h0) = o;
                o.x = O10[4*g+0]; o.y = O10[4*g+1]; o.z = O10[4*g+2]; o.w = O10[4*g+3];
                *(float4*)(Od + (size_t)q0 * HS + 32 + h0) = o;
                o.x = O11[4*g+0]; o.y = O11[4*g+1]; o.z = O11[4*g+2]; o.w = O11[4*g+3];
                *(float4*)(Od + (size_t)q1 * HS + 32 + h0) = o;
            }
            if (hi == 0) {
                Lp[half * ROWS + q0] = l0;
                Lp[half * ROWS + q1] = l1;
            }
        }
    }
}

// ---- reduce: out = sum_h(O_h) / sum_h(l_h) ----
__global__ __launch_bounds__(256) void attn_reduce(
    const float* __restrict__ Op, const float* __restrict__ Lp,
    float* __restrict__ out, int split)
{
    int idx = blockIdx.x * 256 + threadIdx.x;        // float4 index
    int row = idx >> 4;
    float4 s; s.x = s.y = s.z = s.w = 0.f;
    float lsum = 0.f;
    for (int h = 0; h < split; ++h) {
        float4 a = *(const float4*)(Op + (size_t)h * ROWS * HS + (size_t)idx * 4);
        s.x += a.x; s.y += a.y; s.z += a.z; s.w += a.w;
        lsum += Lp[h * ROWS + row];
    }
    float inv = 1.0f / lsum;
    s.x *= inv; s.y *= inv; s.z *= inv; s.w *= inv;
    *(float4*)(out + (size_t)idx * 4) = s;
}

extern "C" void kernel_launch(void* const* d_in, const int* in_sizes, int n_in,
                              void* d_out, int out_size, void* d_ws, size_t ws_size,
                              hipStream_t stream)
{
    const float* x  = (const float*)d_in[0];
    const float* Wq = (const float*)d_in[1];
    const float* Wk = (const float*)d_in[2];
    const float* Wv = (const float*)d_in[3];
    float* out = (float*)d_out;

    char* ws = (char*)d_ws;
    bf16* Qg  = (bf16*)(ws);                          // 2 MB  [16384][64]
    bf16* Kgt = (bf16*)(ws + ((size_t)2 << 20));      // 2 MB  tiled+swizzled
    bf16* Vgt = (bf16*)(ws + ((size_t)4 << 20));      // 2 MB  tiled+swizzled
    bf16* Wt  = (bf16*)(ws + ((size_t)6 << 20));      // 384 KB [192][1024]
    float* Lp = (float*)(ws + ((size_t)6 << 20));     // overlays Wt (dead after proj)
    float* Op = (float*)(ws + ((size_t)6 << 20) + ((size_t)1 << 19));

    const size_t base = ((size_t)6 << 20) + ((size_t)1 << 19);
    int split = 1;
    if (ws_size >= base + (size_t)4 * ROWS * HS * sizeof(float)) split = 4;
    else if (ws_size >= base + (size_t)2 * ROWS * HS * sizeof(float)) split = 2;

    prep_wt<<<48, 256, 0, stream>>>(Wq, Wk, Wv, Wt);
    qkv_proj<<<256, 256, 0, stream>>>(x, Wt, Qg, Kgt, Vgt);
    attn<<<128 * split, 256, 0, stream>>>(Qg, Kgt, Vgt, Op, Lp, out, split);
    if (split > 1)
        attn_reduce<<<(ROWS * HS / 4) / 256, 256, 0, stream>>>(Op, Lp, out, split);
}